// Round 3
// baseline (74.463 us; speedup 1.0000x reference)
//
#include <hip/hip_runtime.h>

// Fused e3nn TensorProduct(uvuv, component-norm) + per-sample o3.Linear.
// x:[B,288]=32x0e+32x1o+32x2e, y:[B,9]=1x0e+1x1o+1x2e, weight:[B,11264], out:[B,288].
//
// Contributing TP paths:
//   l3=0: (0,0,0) (1,1,0) (2,2,0)            -> U=96,  w f4-offset 0
//   l3=1: (0,1,1) (1,0,1) (1,2,1) (2,1,1)    -> U=128, w f4-offset 768
//   l3=2: (0,2,2) (1,1,2) (2,0,2) (2,2,2)    -> U=128, w f4-offset 1792
//
// R3: 4 rows per block, software-pipelined — next row's x/y/w loads are issued
// as the current row's w registers die, so HBM never idles during the
// consume/reduce/store tail. Per-row math identical to R1/R2 (verified).

using f4 = float __attribute__((ext_vector_type(4)));

#define ROWS 4

__device__ inline f4 wred8(f4 v) {
    // reduce over the 8 ug values in this wave (lane bits 3..5); oq=lane&7 kept.
#pragma unroll
    for (int m = 8; m <= 32; m <<= 1) {
        v.x += __shfl_xor(v.x, m);
        v.y += __shfl_xor(v.y, m);
        v.z += __shfl_xor(v.z, m);
        v.w += __shfl_xor(v.w, m);
    }
    return v;
}

__global__ __launch_bounds__(256) void etp_fused(
    const float* __restrict__ xg,
    const float* __restrict__ yg,
    const float* __restrict__ wg,
    float* __restrict__ outg,
    int nrows)
{
    const int t = threadIdx.x;
    const int row0 = blockIdx.x * ROWS;

    __shared__ __align__(16) float xs[288];
    __shared__ float ys[9];
    __shared__ float z0s[96];
    __shared__ float z1s[384];
    __shared__ float z2s[640];
    __shared__ float red[288 * 5];

    const int oq = t & 7;
    const int ug = t >> 3;
    const f4* xg4 = reinterpret_cast<const f4*>(xg);

    // pipeline registers
    f4 xv = {0, 0, 0, 0};
    float yv = 0.f;
    f4 wa0, wa1, wa2, wb0, wb1, wb2, wb3, wc0, wc1, wc2, wc3;

    auto issue_xy = [&](int r) {
        if (t < 72) {
            xv = __builtin_nontemporal_load(&xg4[(size_t)r * 72 + t]);
        } else if (t < 81) {
            yv = yg[(size_t)r * 9 + (t - 72)];
        }
    };
    auto issue_wa = [&](int r) {
        const f4* w4 = reinterpret_cast<const f4*>(wg) + (size_t)r * 2816;
        wa0 = __builtin_nontemporal_load(&w4[(0 * 32 + ug) * 8 + oq]);
        wa1 = __builtin_nontemporal_load(&w4[(1 * 32 + ug) * 8 + oq]);
        wa2 = __builtin_nontemporal_load(&w4[(2 * 32 + ug) * 8 + oq]);
    };
    auto issue_wb = [&](int r) {
        const f4* w4 = reinterpret_cast<const f4*>(wg) + (size_t)r * 2816;
        wb0 = __builtin_nontemporal_load(&w4[768 + (0 * 32 + ug) * 8 + oq]);
        wb1 = __builtin_nontemporal_load(&w4[768 + (1 * 32 + ug) * 8 + oq]);
        wb2 = __builtin_nontemporal_load(&w4[768 + (2 * 32 + ug) * 8 + oq]);
        wb3 = __builtin_nontemporal_load(&w4[768 + (3 * 32 + ug) * 8 + oq]);
    };
    auto issue_wc = [&](int r) {
        const f4* w4 = reinterpret_cast<const f4*>(wg) + (size_t)r * 2816;
        wc0 = __builtin_nontemporal_load(&w4[1792 + (0 * 32 + ug) * 8 + oq]);
        wc1 = __builtin_nontemporal_load(&w4[1792 + (1 * 32 + ug) * 8 + oq]);
        wc2 = __builtin_nontemporal_load(&w4[1792 + (2 * 32 + ug) * 8 + oq]);
        wc3 = __builtin_nontemporal_load(&w4[1792 + (3 * 32 + ug) * 8 + oq]);
    };

    // prologue: row 0 fully issued
    issue_xy(row0);
    issue_wa(row0);
    issue_wb(row0);
    issue_wc(row0);

    // sqrt(2l3+1)-scaled w3j constants
    constexpr float S3  = 0.5477225575051661f;
    constexpr float D3  = 0.31622776601683794f;
    constexpr float TD3 = 0.6324555320336759f;
    constexpr float S5  = 0.7071067811865476f;
    constexpr float D5  = 0.4082482904638631f;
    constexpr float P5  = 0.5345224838248488f;
    constexpr float Q5  = 0.2672612419124244f;
    constexpr float R5  = 0.4629100498862757f;
    constexpr float N3  = 0.5773502691896258f;
    constexpr float N5  = 0.4472135954999579f;

    for (int rr = 0; rr < ROWS; ++rr) {
        const int r = row0 + rr;
        if (r >= nrows) break;
        const bool more = (rr + 1 < ROWS) && (r + 1 < nrows);

        // ---- stage x/y (from pipeline regs) into LDS ----
        if (t < 72) {
            reinterpret_cast<f4*>(xs)[t] = xv;
        } else if (t < 81) {
            ys[t - 72] = yv;
        }
        __syncthreads();   // B1: xs/ys visible

        const float y0 = ys[0];
        const float ya = ys[1], yb = ys[2], yc = ys[3];
        const float Y0 = ys[4], Y1 = ys[5], Y2 = ys[6], Y3 = ys[7], Y4 = ys[8];

        // ---- compute z ----
        if (t < 128) {
            const int u = t;
            float o0, o1, o2;
            if (u < 32) {                       // (0,1,1)
                const float s = xs[u];
                o0 = s * ya; o1 = s * yb; o2 = s * yc;
            } else if (u < 64) {                // (1,0,1)
                const float* p = &xs[32 + 3 * (u - 32)];
                o0 = p[0] * y0; o1 = p[1] * y0; o2 = p[2] * y0;
            } else if (u < 96) {                // (1,2,1)
                const float* p = &xs[32 + 3 * (u - 64)];
                const float a = p[0], bz = p[1], cx = p[2];
                o0 = S3 * (cx * Y0 + bz * Y1 - a * Y4) - D3 * a * Y2;
                o1 = S3 * (a * Y1 + cx * Y3) + TD3 * bz * Y2;
                o2 = S3 * (a * Y0 + bz * Y3 + cx * Y4) - D3 * cx * Y2;
            } else {                            // (2,1,1)
                const float* p = &xs[128 + 5 * (u - 96)];
                const float X0 = p[0], X1 = p[1], X2 = p[2], X3 = p[3], X4 = p[4];
                o0 = S3 * (yc * X0 + yb * X1 - ya * X4) - D3 * ya * X2;
                o1 = S3 * (ya * X1 + yc * X3) + TD3 * yb * X2;
                o2 = S3 * (ya * X0 + yb * X3 + yc * X4) - D3 * yc * X2;
            }
            z1s[3 * u] = o0; z1s[3 * u + 1] = o1; z1s[3 * u + 2] = o2;
        } else {
            const int u = t - 128;
            float c0, c1, c2, c3, c4;
            if (u < 32) {                       // (0,2,2)
                const float s = xs[u];
                c0 = s * Y0; c1 = s * Y1; c2 = s * Y2; c3 = s * Y3; c4 = s * Y4;
            } else if (u < 64) {                // (1,1,2)
                const float* p = &xs[32 + 3 * (u - 32)];
                const float a = p[0], bz = p[1], cx = p[2];
                c0 = S5 * (a * yc + cx * ya);
                c1 = S5 * (a * yb + bz * ya);
                c2 = D5 * (2.0f * bz * yb - a * ya - cx * yc);
                c3 = S5 * (cx * yb + bz * yc);
                c4 = S5 * (cx * yc - a * ya);
            } else if (u < 96) {                // (2,0,2)
                const float* p = &xs[128 + 5 * (u - 64)];
                c0 = p[0] * y0; c1 = p[1] * y0; c2 = p[2] * y0; c3 = p[3] * y0; c4 = p[4] * y0;
            } else {                            // (2,2,2)
                const float* p = &xs[128 + 5 * (u - 96)];
                const float X0 = p[0], X1 = p[1], X2 = p[2], X3 = p[3], X4 = p[4];
                c0 = -P5 * (X0 * Y2 + X2 * Y0) + R5 * (X1 * Y3 + X3 * Y1);
                c1 =  Q5 * (X1 * Y2 + X2 * Y1) - R5 * (X1 * Y4 + X4 * Y1) + R5 * (X0 * Y3 + X3 * Y0);
                c2 =  P5 * (X2 * Y2 - X0 * Y0 - X4 * Y4) + Q5 * (X1 * Y1 + X3 * Y3);
                c3 =  Q5 * (X3 * Y2 + X2 * Y3) + R5 * (X3 * Y4 + X4 * Y3) + R5 * (X0 * Y1 + X1 * Y0);
                c4 = -P5 * (X4 * Y2 + X2 * Y4) + R5 * (X3 * Y3 - X1 * Y1);
            }
            float* zp = &z2s[5 * u];
            zp[0] = c0; zp[1] = c1; zp[2] = c2; zp[3] = c3; zp[4] = c4;
        }
        if (t < 96) {                           // z0 paths
            float v;
            if (t < 32) {
                v = xs[t] * y0;
            } else if (t < 64) {
                const float* p = &xs[32 + 3 * (t - 32)];
                v = N3 * (p[0] * ya + p[1] * yb + p[2] * yc);
            } else {
                const float* p = &xs[128 + 5 * (t - 64)];
                v = N5 * (p[0] * Y0 + p[1] * Y1 + p[2] * Y2 + p[3] * Y3 + p[4] * Y4);
            }
            z0s[t] = v;
        }
        __syncthreads();   // B2: z visible

        const int lane = t & 63;
        const int wv   = t >> 6;
        const int u0 = ug, u1 = 32 + ug, u2 = 64 + ug, u3 = 96 + ug;

        // issue next row's x/y first (oldest in vmcnt queue -> next iter's
        // xs-write waits only for them, leaving w loads in flight)
        if (more) issue_xy(r + 1);

        // ---- l3=0: consume wa, reduce, park, refill wa ----
        {
            f4 a0 = wa0 * z0s[u0] + wa1 * z0s[u1] + wa2 * z0s[u2];
            if (more) issue_wa(r + 1);
            a0 = wred8(a0);
            if (lane < 8) {
                const int o = lane * 4;
#pragma unroll
                for (int j = 0; j < 4; ++j) red[(o + j) * 5 + wv] = a0[j];
            }
        }
        // ---- l3=1: consume wb, reduce, park, refill wb ----
        {
            f4 a1k0 = wb0 * z1s[3*u0]   + wb1 * z1s[3*u1]   + wb2 * z1s[3*u2]   + wb3 * z1s[3*u3];
            f4 a1k1 = wb0 * z1s[3*u0+1] + wb1 * z1s[3*u1+1] + wb2 * z1s[3*u2+1] + wb3 * z1s[3*u3+1];
            f4 a1k2 = wb0 * z1s[3*u0+2] + wb1 * z1s[3*u1+2] + wb2 * z1s[3*u2+2] + wb3 * z1s[3*u3+2];
            if (more) issue_wb(r + 1);
            a1k0 = wred8(a1k0); a1k1 = wred8(a1k1); a1k2 = wred8(a1k2);
            if (lane < 8) {
                const int o = lane * 4;
#pragma unroll
                for (int j = 0; j < 4; ++j) {
                    red[(32 + (o + j) * 3 + 0) * 5 + wv] = a1k0[j];
                    red[(32 + (o + j) * 3 + 1) * 5 + wv] = a1k1[j];
                    red[(32 + (o + j) * 3 + 2) * 5 + wv] = a1k2[j];
                }
            }
        }
        // ---- l3=2: consume wc, reduce, park, refill wc ----
        {
            f4 a2k0 = wc0 * z2s[5*u0]   + wc1 * z2s[5*u1]   + wc2 * z2s[5*u2]   + wc3 * z2s[5*u3];
            f4 a2k1 = wc0 * z2s[5*u0+1] + wc1 * z2s[5*u1+1] + wc2 * z2s[5*u2+1] + wc3 * z2s[5*u3+1];
            f4 a2k2 = wc0 * z2s[5*u0+2] + wc1 * z2s[5*u1+2] + wc2 * z2s[5*u2+2] + wc3 * z2s[5*u3+2];
            f4 a2k3 = wc0 * z2s[5*u0+3] + wc1 * z2s[5*u1+3] + wc2 * z2s[5*u2+3] + wc3 * z2s[5*u3+3];
            f4 a2k4 = wc0 * z2s[5*u0+4] + wc1 * z2s[5*u1+4] + wc2 * z2s[5*u2+4] + wc3 * z2s[5*u3+4];
            if (more) issue_wc(r + 1);
            a2k0 = wred8(a2k0); a2k1 = wred8(a2k1); a2k2 = wred8(a2k2);
            a2k3 = wred8(a2k3); a2k4 = wred8(a2k4);
            if (lane < 8) {
                const int o = lane * 4;
#pragma unroll
                for (int j = 0; j < 4; ++j) {
                    red[(128 + (o + j) * 5 + 0) * 5 + wv] = a2k0[j];
                    red[(128 + (o + j) * 5 + 1) * 5 + wv] = a2k1[j];
                    red[(128 + (o + j) * 5 + 2) * 5 + wv] = a2k2[j];
                    red[(128 + (o + j) * 5 + 3) * 5 + wv] = a2k3[j];
                    red[(128 + (o + j) * 5 + 4) * 5 + wv] = a2k4[j];
                }
            }
        }
        __syncthreads();   // B3: red visible (also fences z/xs reads of this row)

        // ---- final cross-wave sum + scale + store ----
        if (t < 72) {
            const float scale = (t < 8) ? 0.10206207261596575f   // 1/sqrt(96)
                                        : 0.08838834764831845f;  // 1/sqrt(128)
            f4 res;
#pragma unroll
            for (int j = 0; j < 4; ++j) {
                const int idx = 4 * t + j;
                res[j] = (red[idx * 5 + 0] + red[idx * 5 + 1] +
                          red[idx * 5 + 2] + red[idx * 5 + 3]) * scale;
            }
            __builtin_nontemporal_store(res, reinterpret_cast<f4*>(outg) + (size_t)r * 72 + t);
        }
        // next iteration's xs-write is safe without another barrier: all xs/z
        // reads of this row happened before B3; red reads above are by the
        // same threads that then write xs (different buffers).
    }
}

extern "C" void kernel_launch(void* const* d_in, const int* in_sizes, int n_in,
                              void* d_out, int out_size, void* d_ws, size_t ws_size,
                              hipStream_t stream) {
    const float* x = (const float*)d_in[0];
    const float* y = (const float*)d_in[1];
    const float* w = (const float*)d_in[2];
    float* out = (float*)d_out;
    const int nrows = in_sizes[0] / 288;             // 8192
    const int grid = (nrows + ROWS - 1) / ROWS;      // 2048
    etp_fused<<<grid, 256, 0, stream>>>(x, y, w, out, nrows);
}

// Round 4
// 64.204 us; speedup vs baseline: 1.1598x; 1.1598x over previous
//
#include <hip/hip_runtime.h>

// Fused e3nn TensorProduct(uvuv, component-norm) + per-sample o3.Linear.
// x:[B,288]=32x0e+32x1o+32x2e, y:[B,9]=1x0e+1x1o+1x2e, weight:[B,11264], out:[B,288].
//
// Contributing TP paths (match output irreps):
//   l3=0: (0,0,0) (1,1,0) (2,2,0)            -> U=96,  w f4-offset 0
//   l3=1: (0,1,1) (1,0,1) (1,2,1) (2,1,1)    -> U=128, w f4-offset 768
//   l3=2: (0,2,2) (1,1,2) (2,0,2) (2,2,2)    -> U=128, w f4-offset 1792
//
// R4 = R2 verbatim (best: 66.0 us, ~5.9 TB/s effective). R3's intra-block
// 4-row pipeline regressed to 74.5 us -> cross-block TLP already covers the
// latency; keep 8192 independent one-row blocks.

using f4 = float __attribute__((ext_vector_type(4)));

__device__ inline f4 wred8(f4 v) {
    // reduce over lanes differing in bits 3..5 (the 8 ug values in this wave);
    // lane&7 (= oq) is preserved by the xor masks.
#pragma unroll
    for (int m = 8; m <= 32; m <<= 1) {
        v.x += __shfl_xor(v.x, m);
        v.y += __shfl_xor(v.y, m);
        v.z += __shfl_xor(v.z, m);
        v.w += __shfl_xor(v.w, m);
    }
    return v;
}

__global__ __launch_bounds__(256) void etp_fused(
    const float* __restrict__ xg,
    const float* __restrict__ yg,
    const float* __restrict__ wg,
    float* __restrict__ outg)
{
    const int b = blockIdx.x;
    const int t = threadIdx.x;

    __shared__ __align__(16) float xs[288];
    __shared__ float ys[9];
    __shared__ float z0s[96];
    __shared__ float z1s[384];        // [u][k], k=0..2
    __shared__ float z2s[640];        // [u][k], k=0..4
    __shared__ float red[288 * 5];    // [out_idx][wave] wave-partials (stride 5)

    // ---- stage x (float4) and y ----
    if (t < 72) {
        reinterpret_cast<f4*>(xs)[t] =
            __builtin_nontemporal_load(reinterpret_cast<const f4*>(xg) + (size_t)b * 72 + t);
    } else if (t < 81) {
        ys[t - 72] = yg[(size_t)b * 9 + (t - 72)];
    }

    // ---- prefetch ALL weight data now (independent of LDS / barriers) ----
    const int oq = t & 7;       // float4 column group: outputs o = 4*oq .. 4*oq+3
    const int ug = t >> 3;      // u residue class: u = i*32 + ug
    const f4* w4 = reinterpret_cast<const f4*>(wg) + (size_t)b * 2816;

    f4 wa0 = __builtin_nontemporal_load(&w4[(0 * 32 + ug) * 8 + oq]);
    f4 wa1 = __builtin_nontemporal_load(&w4[(1 * 32 + ug) * 8 + oq]);
    f4 wa2 = __builtin_nontemporal_load(&w4[(2 * 32 + ug) * 8 + oq]);
    f4 wb0 = __builtin_nontemporal_load(&w4[768 + (0 * 32 + ug) * 8 + oq]);
    f4 wb1 = __builtin_nontemporal_load(&w4[768 + (1 * 32 + ug) * 8 + oq]);
    f4 wb2 = __builtin_nontemporal_load(&w4[768 + (2 * 32 + ug) * 8 + oq]);
    f4 wb3 = __builtin_nontemporal_load(&w4[768 + (3 * 32 + ug) * 8 + oq]);
    f4 wc0 = __builtin_nontemporal_load(&w4[1792 + (0 * 32 + ug) * 8 + oq]);
    f4 wc1 = __builtin_nontemporal_load(&w4[1792 + (1 * 32 + ug) * 8 + oq]);
    f4 wc2 = __builtin_nontemporal_load(&w4[1792 + (2 * 32 + ug) * 8 + oq]);
    f4 wc3 = __builtin_nontemporal_load(&w4[1792 + (3 * 32 + ug) * 8 + oq]);

    __syncthreads();

    const float y0 = ys[0];
    const float ya = ys[1], yb = ys[2], yc = ys[3];                         // y1 = (y,z,x)
    const float Y0 = ys[4], Y1 = ys[5], Y2 = ys[6], Y3 = ys[7], Y4 = ys[8]; // y2

    // sqrt(2l3+1)-scaled w3j constants
    constexpr float S3  = 0.5477225575051661f;
    constexpr float D3  = 0.31622776601683794f;
    constexpr float TD3 = 0.6324555320336759f;
    constexpr float S5  = 0.7071067811865476f;
    constexpr float D5  = 0.4082482904638631f;
    constexpr float P5  = 0.5345224838248488f;
    constexpr float Q5  = 0.2672612419124244f;
    constexpr float R5  = 0.4629100498862757f;
    constexpr float N3  = 0.5773502691896258f;
    constexpr float N5  = 0.4472135954999579f;

    // ---- compute z (TP intermediate) ----
    if (t < 128) {
        const int u = t;
        float o0, o1, o2;
        if (u < 32) {                       // (0,1,1): x0*y1
            const float s = xs[u];
            o0 = s * ya; o1 = s * yb; o2 = s * yc;
        } else if (u < 64) {                // (1,0,1): x1*y0
            const float* p = &xs[32 + 3 * (u - 32)];
            o0 = p[0] * y0; o1 = p[1] * y0; o2 = p[2] * y0;
        } else if (u < 96) {                // (1,2,1)
            const float* p = &xs[32 + 3 * (u - 64)];
            const float a = p[0], bz = p[1], cx = p[2];
            o0 = S3 * (cx * Y0 + bz * Y1 - a * Y4) - D3 * a * Y2;
            o1 = S3 * (a * Y1 + cx * Y3) + TD3 * bz * Y2;
            o2 = S3 * (a * Y0 + bz * Y3 + cx * Y4) - D3 * cx * Y2;
        } else {                            // (2,1,1)
            const float* p = &xs[128 + 5 * (u - 96)];
            const float X0 = p[0], X1 = p[1], X2 = p[2], X3 = p[3], X4 = p[4];
            o0 = S3 * (yc * X0 + yb * X1 - ya * X4) - D3 * ya * X2;
            o1 = S3 * (ya * X1 + yc * X3) + TD3 * yb * X2;
            o2 = S3 * (ya * X0 + yb * X3 + yc * X4) - D3 * yc * X2;
        }
        z1s[3 * u] = o0; z1s[3 * u + 1] = o1; z1s[3 * u + 2] = o2;
    } else {
        const int u = t - 128;
        float c0, c1, c2, c3, c4;
        if (u < 32) {                       // (0,2,2): x0*y2
            const float s = xs[u];
            c0 = s * Y0; c1 = s * Y1; c2 = s * Y2; c3 = s * Y3; c4 = s * Y4;
        } else if (u < 64) {                // (1,1,2)
            const float* p = &xs[32 + 3 * (u - 32)];
            const float a = p[0], bz = p[1], cx = p[2];
            c0 = S5 * (a * yc + cx * ya);
            c1 = S5 * (a * yb + bz * ya);
            c2 = D5 * (2.0f * bz * yb - a * ya - cx * yc);
            c3 = S5 * (cx * yb + bz * yc);
            c4 = S5 * (cx * yc - a * ya);
        } else if (u < 96) {                // (2,0,2): x2*y0
            const float* p = &xs[128 + 5 * (u - 64)];
            c0 = p[0] * y0; c1 = p[1] * y0; c2 = p[2] * y0; c3 = p[3] * y0; c4 = p[4] * y0;
        } else {                            // (2,2,2)
            const float* p = &xs[128 + 5 * (u - 96)];
            const float X0 = p[0], X1 = p[1], X2 = p[2], X3 = p[3], X4 = p[4];
            c0 = -P5 * (X0 * Y2 + X2 * Y0) + R5 * (X1 * Y3 + X3 * Y1);
            c1 =  Q5 * (X1 * Y2 + X2 * Y1) - R5 * (X1 * Y4 + X4 * Y1) + R5 * (X0 * Y3 + X3 * Y0);
            c2 =  P5 * (X2 * Y2 - X0 * Y0 - X4 * Y4) + Q5 * (X1 * Y1 + X3 * Y3);
            c3 =  Q5 * (X3 * Y2 + X2 * Y3) + R5 * (X3 * Y4 + X4 * Y3) + R5 * (X0 * Y1 + X1 * Y0);
            c4 = -P5 * (X4 * Y2 + X2 * Y4) + R5 * (X3 * Y3 - X1 * Y1);
        }
        float* zp = &z2s[5 * u];
        zp[0] = c0; zp[1] = c1; zp[2] = c2; zp[3] = c3; zp[4] = c4;
    }
    if (t < 96) {                           // z0: (0,0,0),(1,1,0),(2,2,0)
        float v;
        if (t < 32) {
            v = xs[t] * y0;
        } else if (t < 64) {
            const float* p = &xs[32 + 3 * (t - 32)];
            v = N3 * (p[0] * ya + p[1] * yb + p[2] * yc);
        } else {
            const float* p = &xs[128 + 5 * (t - 64)];
            v = N5 * (p[0] * Y0 + p[1] * Y1 + p[2] * Y2 + p[3] * Y3 + p[4] * Y4);
        }
        z0s[t] = v;
    }
    __syncthreads();

    // ---- consume prefetched weights against z from LDS ----
    f4 a0   = wa0 * z0s[ug] + wa1 * z0s[32 + ug] + wa2 * z0s[64 + ug];

    f4 a1k0 = {0,0,0,0}, a1k1 = {0,0,0,0}, a1k2 = {0,0,0,0};
    {
        const f4 w0 = wb0, w1 = wb1, w2 = wb2, w3 = wb3;
        const int u0 = ug, u1 = 32 + ug, u2 = 64 + ug, u3 = 96 + ug;
        a1k0 = w0 * z1s[3*u0]   + w1 * z1s[3*u1]   + w2 * z1s[3*u2]   + w3 * z1s[3*u3];
        a1k1 = w0 * z1s[3*u0+1] + w1 * z1s[3*u1+1] + w2 * z1s[3*u2+1] + w3 * z1s[3*u3+1];
        a1k2 = w0 * z1s[3*u0+2] + w1 * z1s[3*u1+2] + w2 * z1s[3*u2+2] + w3 * z1s[3*u3+2];
    }
    f4 a2k0, a2k1, a2k2, a2k3, a2k4;
    {
        const f4 w0 = wc0, w1 = wc1, w2 = wc2, w3 = wc3;
        const int u0 = ug, u1 = 32 + ug, u2 = 64 + ug, u3 = 96 + ug;
        a2k0 = w0 * z2s[5*u0]   + w1 * z2s[5*u1]   + w2 * z2s[5*u2]   + w3 * z2s[5*u3];
        a2k1 = w0 * z2s[5*u0+1] + w1 * z2s[5*u1+1] + w2 * z2s[5*u2+1] + w3 * z2s[5*u3+1];
        a2k2 = w0 * z2s[5*u0+2] + w1 * z2s[5*u1+2] + w2 * z2s[5*u2+2] + w3 * z2s[5*u3+2];
        a2k3 = w0 * z2s[5*u0+3] + w1 * z2s[5*u1+3] + w2 * z2s[5*u2+3] + w3 * z2s[5*u3+3];
        a2k4 = w0 * z2s[5*u0+4] + w1 * z2s[5*u1+4] + w2 * z2s[5*u2+4] + w3 * z2s[5*u3+4];
    }

    // ---- in-wave reduction over the 8 ug values resident in this wave ----
    a0   = wred8(a0);
    a1k0 = wred8(a1k0); a1k1 = wred8(a1k1); a1k2 = wred8(a1k2);
    a2k0 = wred8(a2k0); a2k1 = wred8(a2k1); a2k2 = wred8(a2k2);
    a2k3 = wred8(a2k3); a2k4 = wred8(a2k4);

    // ---- one representative lane per (wave, oq) writes 36 wave-partials ----
    const int lane = t & 63;
    const int wv   = t >> 6;
    if ((lane >> 3) == 0) {               // lanes 0..7 of each wave; oq == lane
        const int o = lane * 4;
#pragma unroll
        for (int j = 0; j < 4; ++j) {
            red[(o + j) * 5 + wv]                       = a0[j];
            red[(32 + (o + j) * 3 + 0) * 5 + wv]        = a1k0[j];
            red[(32 + (o + j) * 3 + 1) * 5 + wv]        = a1k1[j];
            red[(32 + (o + j) * 3 + 2) * 5 + wv]        = a1k2[j];
            red[(128 + (o + j) * 5 + 0) * 5 + wv]       = a2k0[j];
            red[(128 + (o + j) * 5 + 1) * 5 + wv]       = a2k1[j];
            red[(128 + (o + j) * 5 + 2) * 5 + wv]       = a2k2[j];
            red[(128 + (o + j) * 5 + 3) * 5 + wv]       = a2k3[j];
            red[(128 + (o + j) * 5 + 4) * 5 + wv]       = a2k4[j];
        }
    }
    __syncthreads();

    // ---- final cross-wave sum (4 partials) + scale + direct f4 store ----
    if (t < 72) {
        const float scale = (t < 8) ? 0.10206207261596575f   // 1/sqrt(96)
                                    : 0.08838834764831845f;  // 1/sqrt(128)
        f4 r;
#pragma unroll
        for (int j = 0; j < 4; ++j) {
            const int idx = 4 * t + j;
            r[j] = (red[idx * 5 + 0] + red[idx * 5 + 1] +
                    red[idx * 5 + 2] + red[idx * 5 + 3]) * scale;
        }
        __builtin_nontemporal_store(r, reinterpret_cast<f4*>(outg) + (size_t)b * 72 + t);
    }
}

extern "C" void kernel_launch(void* const* d_in, const int* in_sizes, int n_in,
                              void* d_out, int out_size, void* d_ws, size_t ws_size,
                              hipStream_t stream) {
    const float* x = (const float*)d_in[0];
    const float* y = (const float*)d_in[1];
    const float* w = (const float*)d_in[2];
    float* out = (float*)d_out;
    const int rows = in_sizes[0] / 288;   // 8192
    etp_fused<<<rows, 256, 0, stream>>>(x, y, w, out);
}